// Round 1
// baseline (191.047 us; speedup 1.0000x reference)
//
#include <hip/hip_runtime.h>

#define NNODES 4096
#define NEDGES 500000
#define NPAIRS 2000000
#define EDIM   16
#define LMAX   5

// ---------------------------------------------------------------------------
// Kernel 0: dots[l*NEDGES + e] = dot(edge_attr[e,:], edge_weights[l,:])
// Turns the 64B-per-hop gather into a 4B-per-hop gather downstream.
// ---------------------------------------------------------------------------
__global__ __launch_bounds__(256) void dots_kernel(
    const float* __restrict__ edge_attr,
    const float* __restrict__ ew,
    float* __restrict__ dots) {
  __shared__ float w[LMAX * EDIM];
  int tid = threadIdx.x;
  if (tid < LMAX * EDIM) w[tid] = ew[tid];
  __syncthreads();

  int e = blockIdx.x * 256 + tid;
  if (e >= NEDGES) return;

  const float4* row = (const float4*)(edge_attr + (size_t)e * EDIM);
  float4 r0 = row[0], r1 = row[1], r2 = row[2], r3 = row[3];
  float v[16] = {r0.x, r0.y, r0.z, r0.w,
                 r1.x, r1.y, r1.z, r1.w,
                 r2.x, r2.y, r2.z, r2.w,
                 r3.x, r3.y, r3.z, r3.w};
#pragma unroll
  for (int l = 0; l < LMAX; ++l) {
    float d = 0.f;
#pragma unroll
    for (int k = 0; k < EDIM; ++k) d += v[k] * w[l * EDIM + k];
    dots[l * NEDGES + e] = d;  // coalesced per l
  }
}

// ---------------------------------------------------------------------------
// Kernel 1: mean[p] = (1/len) * sum_{l<len} dots[l][path_idx[p,l]]
// Coalesced reads of lens/idx; 4B gathers into the l-th 2MB dots slab
// (all lanes on the same l at the same time -> L2-friendly).
// ---------------------------------------------------------------------------
__global__ __launch_bounds__(256) void mean_kernel(
    const int* __restrict__ path_idx,
    const int* __restrict__ path_lens,
    const float* __restrict__ dots,
    float* __restrict__ mean) {
  int p = blockIdx.x * 256 + threadIdx.x;
  if (p >= NPAIRS) return;

  int len = path_lens[p];
  len = min(max(len, 0), LMAX);

  const int* row = path_idx + (size_t)p * LMAX;
  float s = 0.f;
  for (int l = 0; l < len; ++l) {
    int idx = row[l];
    s += dots[l * NEDGES + idx];
  }
  mean[p] = (len > 0) ? (s / (float)len) : 0.f;
}

// ---------------------------------------------------------------------------
// Kernel 2: out[src*N + dst] = (p = dst*N+src < NPAIRS) ? mean[p] : 0
// LDS-tiled transpose: coalesced 256B reads of mean, coalesced writes of the
// full 67MB output (exactly once per element -> no memset pass needed).
// Tiles entirely past the valid region skip LDS and just zero-fill.
// ---------------------------------------------------------------------------
__global__ __launch_bounds__(256) void expand_transpose(
    const float* __restrict__ mean,
    float* __restrict__ out) {
  const int dst0 = blockIdx.x * 64;
  const int src0 = blockIdx.y * 64;
  const int tx = threadIdx.x;  // 0..63
  const int ty = threadIdx.y;  // 0..3

  if (dst0 * NNODES + src0 >= NPAIRS) {
    // whole tile invalid -> zero fill, coalesced
#pragma unroll
    for (int r = 0; r < 16; ++r) {
      int src = src0 + ty + r * 4;
      out[(size_t)src * NNODES + dst0 + tx] = 0.f;
    }
    return;
  }

  __shared__ float tile[64][65];  // +1 pad: store-phase stride 65 -> conflict-free

#pragma unroll
  for (int r = 0; r < 16; ++r) {
    int a = ty + r * 4;                       // dst offset in tile
    int p = (dst0 + a) * NNODES + src0 + tx;  // < 2^31, fits int
    tile[a][tx] = (p < NPAIRS) ? mean[p] : 0.f;
  }
  __syncthreads();
#pragma unroll
  for (int r = 0; r < 16; ++r) {
    int a = ty + r * 4;  // src offset in tile
    out[(size_t)(src0 + a) * NNODES + dst0 + tx] = tile[tx][a];
  }
}

// ---------------------------------------------------------------------------
// Fallback (only if ws_size < 18MB): memset + direct scatter from edge_attr.
// ---------------------------------------------------------------------------
__global__ __launch_bounds__(256) void scatter_kernel(
    const float* __restrict__ edge_attr,
    const float* __restrict__ ew,
    const int* __restrict__ path_idx,
    const int* __restrict__ path_lens,
    float* __restrict__ out) {
  __shared__ float w[LMAX * EDIM];
  if (threadIdx.x < LMAX * EDIM) w[threadIdx.x] = ew[threadIdx.x];
  __syncthreads();

  int p = blockIdx.x * 256 + threadIdx.x;
  if (p >= NPAIRS) return;

  int len = path_lens[p];
  len = min(max(len, 0), LMAX);

  const int* row = path_idx + (size_t)p * LMAX;
  float s = 0.f;
  for (int l = 0; l < len; ++l) {
    int idx = row[l];
    const float4* r = (const float4*)(edge_attr + (size_t)idx * EDIM);
    float4 a0 = r[0], a1 = r[1], a2 = r[2], a3 = r[3];
    const float* wl = &w[l * EDIM];
    float d = a0.x * wl[0] + a0.y * wl[1] + a0.z * wl[2] + a0.w * wl[3] +
              a1.x * wl[4] + a1.y * wl[5] + a1.z * wl[6] + a1.w * wl[7] +
              a2.x * wl[8] + a2.y * wl[9] + a2.z * wl[10] + a2.w * wl[11] +
              a3.x * wl[12] + a3.y * wl[13] + a3.z * wl[14] + a3.w * wl[15];
    s += d;
  }
  float m = (len > 0) ? (s / (float)len) : 0.f;
  int src = p & (NNODES - 1);
  int dst = p >> 12;
  out[(size_t)src * NNODES + dst] = m;
}

extern "C" void kernel_launch(void* const* d_in, const int* in_sizes, int n_in,
                              void* d_out, int out_size, void* d_ws, size_t ws_size,
                              hipStream_t stream) {
  // setup_inputs order: x, edge_attr, edge_weights, path_idx, path_lens, pair_id
  const float* edge_attr = (const float*)d_in[1];
  const float* edge_w    = (const float*)d_in[2];
  const int*   path_idx  = (const int*)d_in[3];
  const int*   path_lens = (const int*)d_in[4];
  float* out = (float*)d_out;

  const size_t need = (size_t)LMAX * NEDGES * sizeof(float) +
                      (size_t)NPAIRS * sizeof(float);  // 10MB + 8MB

  if (ws_size >= need) {
    float* dots = (float*)d_ws;
    float* mean = dots + (size_t)LMAX * NEDGES;

    dots_kernel<<<(NEDGES + 255) / 256, 256, 0, stream>>>(edge_attr, edge_w, dots);
    mean_kernel<<<(NPAIRS + 255) / 256, 256, 0, stream>>>(path_idx, path_lens, dots, mean);
    dim3 grid(64, 64), block(64, 4);
    expand_transpose<<<grid, block, 0, stream>>>(mean, out);
  } else {
    hipMemsetAsync(d_out, 0, (size_t)out_size * sizeof(float), stream);
    scatter_kernel<<<(NPAIRS + 255) / 256, 256, 0, stream>>>(
        edge_attr, edge_w, path_idx, path_lens, out);
  }
}

// Round 2
// 175.734 us; speedup vs baseline: 1.0871x; 1.0871x over previous
//
#include <hip/hip_runtime.h>
#include <hip/hip_fp16.h>

#define NNODES 4096
#define NEDGES 500000
#define NPAIRS 2000000
#define EDIM   16
#define LMAX   5

// ---------------------------------------------------------------------------
// Kernel 0: dots[l*NEDGES + e] = fp16(dot(edge_attr[e,:], edge_weights[l,:]))
// 2 edges/thread -> half2 stores (4B/lane, 256B/wave per slab).
// fp16 halves the downstream gather footprint (5MB total, ~L2-resident/XCD).
// ---------------------------------------------------------------------------
__global__ __launch_bounds__(256) void dots_kernel(
    const float* __restrict__ edge_attr,
    const float* __restrict__ ew,
    __half* __restrict__ dots) {
  __shared__ float w[LMAX * EDIM];
  int tid = threadIdx.x;
  if (tid < LMAX * EDIM) w[tid] = ew[tid];
  __syncthreads();

  int e0 = (blockIdx.x * 256 + tid) * 2;  // NEDGES even -> e0+1 always valid
  if (e0 >= NEDGES) return;

  const float4* ra = (const float4*)(edge_attr + (size_t)e0 * EDIM);
  float4 a0 = ra[0], a1 = ra[1], a2 = ra[2], a3 = ra[3];
  float4 b0 = ra[4], b1 = ra[5], b2 = ra[6], b3 = ra[7];  // edge e0+1
  float va[16] = {a0.x, a0.y, a0.z, a0.w, a1.x, a1.y, a1.z, a1.w,
                  a2.x, a2.y, a2.z, a2.w, a3.x, a3.y, a3.z, a3.w};
  float vb[16] = {b0.x, b0.y, b0.z, b0.w, b1.x, b1.y, b1.z, b1.w,
                  b2.x, b2.y, b2.z, b2.w, b3.x, b3.y, b3.z, b3.w};
#pragma unroll
  for (int l = 0; l < LMAX; ++l) {
    float da = 0.f, db = 0.f;
#pragma unroll
    for (int k = 0; k < EDIM; ++k) {
      da += va[k] * w[l * EDIM + k];
      db += vb[k] * w[l * EDIM + k];
    }
    __half2 h;
    h.x = __float2half(da);
    h.y = __float2half(db);
    *(__half2*)(dots + (size_t)l * NEDGES + e0) = h;  // e0 even -> 4B aligned
  }
}

// ---------------------------------------------------------------------------
// Kernel 1: mean[p] = (1/len) * sum_{l<len} dots[l][path_idx[p,l]]
// NT loads for the 48MB idx/lens stream (protect dots slabs in L2);
// all 5 idx preloaded unconditionally (same cache lines either way) so the
// conditional 2B gathers can all be in flight together.
// ---------------------------------------------------------------------------
__global__ __launch_bounds__(256) void mean_kernel(
    const int* __restrict__ path_idx,
    const int* __restrict__ path_lens,
    const __half* __restrict__ dots,
    float* __restrict__ mean) {
  int p = blockIdx.x * 256 + threadIdx.x;
  if (p >= NPAIRS) return;

  int len = __builtin_nontemporal_load(path_lens + p);
  len = min(max(len, 0), LMAX);

  const int* row = path_idx + (size_t)p * LMAX;
  int i0 = __builtin_nontemporal_load(row + 0);
  int i1 = __builtin_nontemporal_load(row + 1);
  int i2 = __builtin_nontemporal_load(row + 2);
  int i3 = __builtin_nontemporal_load(row + 3);
  int i4 = __builtin_nontemporal_load(row + 4);

  float s = 0.f;
  if (len > 0) s += __half2float(dots[i0]);
  if (len > 1) s += __half2float(dots[1 * NEDGES + i1]);
  if (len > 2) s += __half2float(dots[2 * NEDGES + i2]);
  if (len > 3) s += __half2float(dots[3 * NEDGES + i3]);
  if (len > 4) s += __half2float(dots[4 * NEDGES + i4]);

  mean[p] = (len > 0) ? (s / (float)len) : 0.f;
}

// ---------------------------------------------------------------------------
// Kernel 2: out[src*N + dst] = (p = dst*N+src < NPAIRS) ? mean[p] : 0
// float4 on both global phases; LDS tile stride 65 (scalar ds ops, 2-way max
// bank aliasing = free). NPAIRS boundary is 16B-aligned so float4 validity
// checks are exact. Every output element written exactly once.
// ---------------------------------------------------------------------------
__global__ __launch_bounds__(256) void expand_transpose(
    const float* __restrict__ mean,
    float* __restrict__ out) {
  const int dst0 = blockIdx.x * 64;
  const int src0 = blockIdx.y * 64;
  const int tid = threadIdx.x;  // 0..255

  if (dst0 * NNODES >= NPAIRS) {  // whole tile past valid region
    float4 z = {0.f, 0.f, 0.f, 0.f};
#pragma unroll
    for (int i = 0; i < 4; ++i) {
      int slot = tid + i * 256;  // 0..1023
      int a = slot >> 4;         // src row 0..63
      int c = slot & 15;         // float4 col
      ((float4*)(out + (size_t)(src0 + a) * NNODES + dst0))[c] = z;
    }
    return;
  }

  __shared__ float tile[64][65];

#pragma unroll
  for (int i = 0; i < 4; ++i) {
    int slot = tid + i * 256;
    int a = slot >> 4;  // dst offset
    int c = slot & 15;
    int p = (dst0 + a) * NNODES + src0 + 4 * c;  // multiple of 4
    float4 v;
    if (p < NPAIRS) v = *(const float4*)(mean + p);
    else { v.x = 0.f; v.y = 0.f; v.z = 0.f; v.w = 0.f; }
    tile[a][4 * c + 0] = v.x;
    tile[a][4 * c + 1] = v.y;
    tile[a][4 * c + 2] = v.z;
    tile[a][4 * c + 3] = v.w;
  }
  __syncthreads();
#pragma unroll
  for (int i = 0; i < 4; ++i) {
    int slot = tid + i * 256;
    int a = slot >> 4;  // src offset
    int c = slot & 15;
    float4 v;
    v.x = tile[4 * c + 0][a];
    v.y = tile[4 * c + 1][a];
    v.z = tile[4 * c + 2][a];
    v.w = tile[4 * c + 3][a];
    ((float4*)(out + (size_t)(src0 + a) * NNODES + dst0))[c] = v;
  }
}

// ---------------------------------------------------------------------------
// Fallback (ws too small): memset + direct fp32 scatter.
// ---------------------------------------------------------------------------
__global__ __launch_bounds__(256) void scatter_kernel(
    const float* __restrict__ edge_attr,
    const float* __restrict__ ew,
    const int* __restrict__ path_idx,
    const int* __restrict__ path_lens,
    float* __restrict__ out) {
  __shared__ float w[LMAX * EDIM];
  if (threadIdx.x < LMAX * EDIM) w[threadIdx.x] = ew[threadIdx.x];
  __syncthreads();

  int p = blockIdx.x * 256 + threadIdx.x;
  if (p >= NPAIRS) return;

  int len = path_lens[p];
  len = min(max(len, 0), LMAX);

  const int* row = path_idx + (size_t)p * LMAX;
  float s = 0.f;
  for (int l = 0; l < len; ++l) {
    int idx = row[l];
    const float4* r = (const float4*)(edge_attr + (size_t)idx * EDIM);
    float4 a0 = r[0], a1 = r[1], a2 = r[2], a3 = r[3];
    const float* wl = &w[l * EDIM];
    s += a0.x * wl[0] + a0.y * wl[1] + a0.z * wl[2] + a0.w * wl[3] +
         a1.x * wl[4] + a1.y * wl[5] + a1.z * wl[6] + a1.w * wl[7] +
         a2.x * wl[8] + a2.y * wl[9] + a2.z * wl[10] + a2.w * wl[11] +
         a3.x * wl[12] + a3.y * wl[13] + a3.z * wl[14] + a3.w * wl[15];
  }
  float m = (len > 0) ? (s / (float)len) : 0.f;
  int src = p & (NNODES - 1);
  int dst = p >> 12;
  out[(size_t)src * NNODES + dst] = m;
}

extern "C" void kernel_launch(void* const* d_in, const int* in_sizes, int n_in,
                              void* d_out, int out_size, void* d_ws, size_t ws_size,
                              hipStream_t stream) {
  // setup_inputs order: x, edge_attr, edge_weights, path_idx, path_lens, pair_id
  const float* edge_attr = (const float*)d_in[1];
  const float* edge_w    = (const float*)d_in[2];
  const int*   path_idx  = (const int*)d_in[3];
  const int*   path_lens = (const int*)d_in[4];
  float* out = (float*)d_out;

  // ws layout: mean (8MB, 16B-aligned for float4 reads) then dots fp16 (5MB)
  const size_t need = (size_t)NPAIRS * sizeof(float) +
                      (size_t)LMAX * NEDGES * sizeof(__half);

  if (ws_size >= need) {
    float* mean = (float*)d_ws;
    __half* dots = (__half*)((char*)d_ws + (size_t)NPAIRS * sizeof(float));

    dots_kernel<<<(NEDGES / 2 + 255) / 256, 256, 0, stream>>>(edge_attr, edge_w, dots);
    mean_kernel<<<(NPAIRS + 255) / 256, 256, 0, stream>>>(path_idx, path_lens, dots, mean);
    dim3 grid(64, 64), block(256, 1);
    expand_transpose<<<grid, block, 0, stream>>>(mean, out);
  } else {
    hipMemsetAsync(d_out, 0, (size_t)out_size * sizeof(float), stream);
    scatter_kernel<<<(NPAIRS + 255) / 256, 256, 0, stream>>>(
        edge_attr, edge_w, path_idx, path_lens, out);
  }
}